// Round 8
// baseline (1937.664 us; speedup 1.0000x reference)
//
#include <hip/hip_runtime.h>

// ---------------------------------------------------------------------------
// LSTM: B=64, SEQ=512, I=1024, H=1024, O=512, fp32 in/out.
// Row space: n' = hid*4 + gate (gate-interleaved) so MFMA C-layout puts all
// 4 gate preacts of one (hid,batch) in ONE lane (acc[rr] = gate rr).
//   prep: pack Wh4/Wx4 -> bf16 [n'=4096][1024], bias[n'], X->bf16,
//         h0 chunk-layout buffer + poison bufs 1..3, wT for output GEMM
//   R14:  R13 + WAVE SPECIALIZATION. R13 evidence: per-step 7660cy = 1080
//         MFMA + ~1650 VALU + ~4900 latency; 256thr/block = 1 wave/SIMD
//         (zero TLP, all latency exposed) and MFMA-x sat ON the critical
//         path between store and next poll. FETCH-units corrected: polls
//         are L3-side, never HBM -- FETCH was Xg/Xb all along.
//         R14: 512 thr = 8 waves (2/SIMD). Waves 0-3 = recurrence (R13's
//         exact poll/stage/MFMA-h/gates/store). Waves 4-7 = x-pipeline:
//         in the POLL WINDOW they compute xg(t+1) (MFMA-x) into a dbuf
//         LDS array; during MFMA-h they gld x(t+2) -> xTl. One afrag[32]
//         loaded from Wh or Wx by wave role (same regs). Removes MFMA-x
//         from the critical path AND fills poll-stall cycles with x-work.
//         Both groups hit the same 2 barriers/step (no divergent-barrier
//         deadlock). xgbuf[2] parity: written P(t) by x-waves, read C(t+1)
//         by h-waves -- separated by bar1/bar2 chain. xTl: read P(t) by
//         x-waves, overwritten C(t) (gld after bar1), per-x-wave vmcnt(0)
//         before bar2 => all gld landed before next P reads.
//         Exchange protocol identical to R13 (poison data-poll, 4 bufs,
//         chunk stores = 4 full 128B lines). LDS 74.9KB (plain launch;
//         isolates R12's LDS-vs-coop failure variable).
//   out:  out[b][o] = h[b,:] . w[o,:]  (chunk-layout translated)
// ---------------------------------------------------------------------------

typedef short short8 __attribute__((ext_vector_type(8)));   // 8 bf16
typedef float f32x4 __attribute__((ext_vector_type(4)));

typedef __attribute__((address_space(1))) const unsigned int glb_u32;
typedef __attribute__((address_space(3))) unsigned int lds_u32;

#define SEQL  512
#define POISON 0xFFFFFFFFFFFFFFFFull
#define BUFU64 16384     // u64 per h buffer: 4 groups x 64 chunks x 64 u64

__device__ __forceinline__ unsigned short f2bf(float f) {
    unsigned int u = __builtin_bit_cast(unsigned int, f);
    u += 0x7FFFu + ((u >> 16) & 1u);            // round-to-nearest-even
    return (unsigned short)(u >> 16);
}
__device__ __forceinline__ float bf2f(unsigned short s) {
    unsigned int u = ((unsigned int)s) << 16;
    return __builtin_bit_cast(float, u);
}
__device__ __forceinline__ float sigmoidf_fast(float x) {
    return 1.f / (1.f + __expf(-x));
}
__device__ __forceinline__ float tanhf_fast(float x) {
    return 1.f - 2.f / (1.f + __expf(2.f * x));
}
__device__ __forceinline__ void gld_lds16(const unsigned short* g, unsigned short* l) {
    __builtin_amdgcn_global_load_lds((glb_u32*)g, (lds_u32*)l, 16, 0, 0);
}

// --- prep: pack 4 gate weight mats (fp32 [1024][1024]) into bf16 [n'][1024]
__global__ void k_pack_w(const float* __restrict__ w0, const float* __restrict__ w1,
                         const float* __restrict__ w2, const float* __restrict__ w3,
                         unsigned short* __restrict__ dst) {
    int idx4 = blockIdx.x * blockDim.x + threadIdx.x;   // over 4096*256
    int np = idx4 >> 8;            // n' 0..4095
    int k4 = (idx4 & 255) * 4;
    int g = np & 3, r = np >> 2;
    const float* src = (g == 0) ? w0 : (g == 1) ? w1 : (g == 2) ? w2 : w3;
    float4 v = *(const float4*)(src + r * 1024 + k4);
    ushort4 o;
    o.x = f2bf(v.x); o.y = f2bf(v.y); o.z = f2bf(v.z); o.w = f2bf(v.w);
    *(ushort4*)(dst + (size_t)np * 1024 + k4) = o;
}

// --- prep: bias[n'], h0 -> buf0 chunk layout, poison bufs 1..3, wT
__global__ void k_misc(const float* __restrict__ b_hi, const float* __restrict__ b_xi,
                       const float* __restrict__ b_hf, const float* __restrict__ b_xf,
                       const float* __restrict__ b_ho, const float* __restrict__ b_xo,
                       const float* __restrict__ b_hg, const float* __restrict__ b_xg,
                       const float* __restrict__ h0, const float* __restrict__ w,
                       float* __restrict__ bias, unsigned short* __restrict__ hbuf,
                       float* __restrict__ wT) {
    int idx = blockIdx.x * blockDim.x + threadIdx.x;
    if (idx < 4096) {
        int g = idx & 3, r = idx >> 2;                  // n'-order bias
        const float* bh = (g == 0) ? b_hi : (g == 1) ? b_hf : (g == 2) ? b_ho : b_hg;
        const float* bx = (g == 0) ? b_xi : (g == 1) ? b_xf : (g == 2) ? b_xo : b_xg;
        bias[idx] = bh[r] + bx[r];
    } else if (idx < 4096 + 65536) {
        int e = idx - 4096;              // buf0 short idx: [cg][b16][hid16]
        int cg = e >> 8;                 // jb*64 + ibb
        int h16 = e & 15;
        hbuf[e] = f2bf(h0[(cg & 63) * 16 + h16]);   // hid = ibb*16 + h16
    } else if (idx < 4096 + 65536 + 524288) {
        int e = idx - 69632;
        int k = e >> 9, o = e & 511;
        wT[e] = w[o * 1024 + k];
    } else if (idx < 4096 + 65536 + 524288 + 3 * BUFU64) {
        int e = idx - (4096 + 65536 + 524288);          // poison bufs 1..3
        ((unsigned long long*)hbuf)[BUFU64 + e] = POISON;
    }
}

// --- prep: X fp32 -> bf16 (layout [b][t][k] preserved)
__global__ void k_convert_x(const float* __restrict__ X, unsigned short* __restrict__ Xb) {
    int idx = blockIdx.x * blockDim.x + threadIdx.x;
    float4 v = ((const float4*)X)[idx];
    ushort4 o;
    o.x = f2bf(v.x); o.y = f2bf(v.y); o.z = f2bf(v.z); o.w = f2bf(v.w);
    ((ushort4*)Xb)[idx] = o;
}

// --- fused persistent recurrence (R14: wave-specialized).
// 256 blocks x 512 thr: jb=blk&3 (16 batches), ibb=blk>>2 (0..63): n' rows
// [ibb*64,+64) = 16 hids x 4 gates. Wave w: role = h (w<4) or x (w>=4);
// wq=w&3 -> rows ibb*64+wq*16+[0,16). Lane (lq,l15): acc[rr] = gate-rr
// preact for hid=ibb*16+wq*4+lq, b=jb*16+l15. x-wave wq computes exactly
// the xg its counterpart h-wave wq needs, same lane layout.
// h chunk (512B) = u64[(jb*64+ibb)*64 + b16*4 + l4] holding hids l4*4..+4.
__global__ __launch_bounds__(512, 1) void k_rec(const unsigned short* __restrict__ Wh,
                                                const unsigned short* __restrict__ Wx,
                                                const unsigned short* __restrict__ Xb,
                                                const float* __restrict__ bias,
                                                const float* __restrict__ c0,
                                                unsigned short* __restrict__ hbuf) {
    const int blk = blockIdx.x;
    const int jb  = blk & 3;
    const int ibb = blk >> 2;
    const int tid = threadIdx.x;
    const int w   = tid >> 6;        // 0..7
    const int wq  = w & 3;
    const bool hw = (w < 4);
    const int l   = tid & 63;
    const int l15 = l & 15, lq = l >> 4;

    __shared__ unsigned short hTl[16 * 1032];   // h(t) tile [b16][k=1024]
    __shared__ unsigned short xTl[16 * 1032];   // x tile (single buffer)
    __shared__ f32x4 xgbuf[2][256];             // [parity][wq*64 + l]
    __shared__ unsigned short hTr[16 * 20];     // h out [b16][hid16], pad 20

    // Role-dependent persistent A-fragments: h-waves <- Wh, x-waves <- Wx.
    // Same registers either way (one array). R3-proven pin.
    short8 afrag[32];
    {
        const unsigned short* wsrc = hw ? Wh : Wx;
        const unsigned short* wrow = wsrc + (size_t)(ibb * 64 + wq * 16 + l15) * 1024;
#pragma unroll
        for (int ks = 0; ks < 32; ++ks)
            afrag[ks] = *(const short8*)(wrow + ks * 32 + lq * 8);
#pragma unroll
        for (int ks = 0; ks < 32; ++ks)
            asm volatile("" : "+v"(afrag[ks]));
    }

    const int hid = ibb * 16 + wq * 4 + lq;
    float c = c0[hid];                          // used by h-waves only
    float bias4[4];                             // used by x-waves only
#pragma unroll
    for (int rr = 0; rr < 4; ++rr)
        bias4[rr] = bias[(size_t)ibb * 64 + wq * 16 + lq * 4 + rr];

    unsigned long long* hb64 = (unsigned long long*)hbuf;

    // h stage mapping (h-waves, tid 0..255): thread handles u64 g=p*256+tid;
    // decode: chunk p*4+w, batch (tid>>2)&15, l4 tid&3 -> LDS k = p*64+w*16+l4*4.
    const int stage_sh = ((tid >> 2) & 15) * 1032 + wq * 16 + (tid & 3) * 4;

    for (int t = -3; t < SEQL; ++t) {
        // ===================== region P =====================
        if (t >= 0) {
            if (hw) {
                // --- poll + stage h(t) (data arrival IS the flag) ---
                const unsigned long long* src =
                    hb64 + (size_t)(t & 3) * BUFU64 + (size_t)jb * 4096 + tid;
                unsigned long long tmp[16];
#pragma unroll
                for (int p = 0; p < 16; ++p)
                    tmp[p] = __hip_atomic_load(src + p * 256, __ATOMIC_RELAXED,
                                               __HIP_MEMORY_SCOPE_AGENT);
                for (;;) {
                    unsigned miss = 0;
#pragma unroll
                    for (int p = 0; p < 16; ++p)
                        if (tmp[p] == POISON) miss |= 1u << p;
                    if (!miss) break;
                    __builtin_amdgcn_s_sleep(1);
#pragma unroll
                    for (int p = 0; p < 16; ++p)
                        if (miss & (1u << p))
                            tmp[p] = __hip_atomic_load(src + p * 256, __ATOMIC_RELAXED,
                                                       __HIP_MEMORY_SCOPE_AGENT);
                }
#pragma unroll
                for (int p = 0; p < 16; ++p)
                    *(unsigned long long*)(&hTl[stage_sh + p * 64]) = tmp[p];
            } else if (t < SEQL - 1) {
                // --- MFMA-x: xg(t+1) from xTl (holds x(t+1)) -> xgbuf ---
                f32x4 xa0 = {0.f, 0.f, 0.f, 0.f}, xa1 = {0.f, 0.f, 0.f, 0.f};
#pragma unroll
                for (int ks = 0; ks < 32; ks += 2) {
                    short8 b0 = *(const short8*)(&xTl[l15 * 1032 + ks * 32 + lq * 8]);
                    short8 b1 = *(const short8*)(&xTl[l15 * 1032 + (ks + 1) * 32 + lq * 8]);
                    xa0 = __builtin_amdgcn_mfma_f32_16x16x32_bf16(afrag[ks], b0, xa0, 0, 0, 0);
                    xa1 = __builtin_amdgcn_mfma_f32_16x16x32_bf16(afrag[ks + 1], b1, xa1, 0, 0, 0);
                }
                f32x4 xg4;
#pragma unroll
                for (int rr = 0; rr < 4; ++rr)
                    xg4[rr] = xa0[rr] + xa1[rr] + bias4[rr];
                xgbuf[(t + 1) & 1][wq * 64 + l] = xg4;
            }
        } else if (t == -3 || t == -1) {
            // prologue P: stage x(0) (t=-3) / x(1) (t=-1) into xTl
            if (!hw) {
                const int tt = (t == -3) ? 0 : 1;
#pragma unroll
                for (int i = 0; i < 8; ++i) {
                    int r = wq * 8 + i, b16 = r >> 1, half = r & 1;
                    const unsigned short* src =
                        Xb + ((size_t)(jb * 16 + b16) * 512 + tt) * 1024 + half * 512 + l * 8;
                    gld_lds16(src, &xTl[b16 * 1032 + half * 512]);
                }
                asm volatile("s_waitcnt vmcnt(0)" ::: "memory");
            }
        } else {   // t == -2: prologue compute xg(0) -> xgbuf[0]
            if (!hw) {
                f32x4 xa0 = {0.f, 0.f, 0.f, 0.f}, xa1 = {0.f, 0.f, 0.f, 0.f};
#pragma unroll
                for (int ks = 0; ks < 32; ks += 2) {
                    short8 b0 = *(const short8*)(&xTl[l15 * 1032 + ks * 32 + lq * 8]);
                    short8 b1 = *(const short8*)(&xTl[l15 * 1032 + (ks + 1) * 32 + lq * 8]);
                    xa0 = __builtin_amdgcn_mfma_f32_16x16x32_bf16(afrag[ks], b0, xa0, 0, 0, 0);
                    xa1 = __builtin_amdgcn_mfma_f32_16x16x32_bf16(afrag[ks + 1], b1, xa1, 0, 0, 0);
                }
                f32x4 xg4;
#pragma unroll
                for (int rr = 0; rr < 4; ++rr)
                    xg4[rr] = xa0[rr] + xa1[rr] + bias4[rr];
                xgbuf[0][wq * 64 + l] = xg4;
            }
        }
        __syncthreads();   // bar1
        if (t < 0) continue;   // prologue: single-barrier cadence

        // ===================== region C =====================
        if (hw) {
            f32x4 xg4 = xgbuf[t & 1][wq * 64 + l];
            f32x4 a0 = {0.f, 0.f, 0.f, 0.f}, a1 = {0.f, 0.f, 0.f, 0.f};
#pragma unroll
            for (int ks = 0; ks < 32; ks += 2) {
                short8 b0 = *(const short8*)(&hTl[l15 * 1032 + ks * 32 + lq * 8]);
                short8 b1 = *(const short8*)(&hTl[l15 * 1032 + (ks + 1) * 32 + lq * 8]);
                a0 = __builtin_amdgcn_mfma_f32_16x16x32_bf16(afrag[ks], b0, a0, 0, 0, 0);
                a1 = __builtin_amdgcn_mfma_f32_16x16x32_bf16(afrag[ks + 1], b1, a1, 0, 0, 0);
            }
            float pi = a0[0] + a1[0] + xg4[0];
            float pf = a0[1] + a1[1] + xg4[1];
            float po = a0[2] + a1[2] + xg4[2];
            float pg = a0[3] + a1[3] + xg4[3];
            float ig = sigmoidf_fast(pi);
            float fg = sigmoidf_fast(pf);
            float og = sigmoidf_fast(po);
            float gg = tanhf_fast(pg);
            c = fg * c + ig * gg;
            float hh = og * tanhf_fast(c);
            hTr[l15 * 20 + wq * 4 + lq] = f2bf(hh);
        } else {
            // prefetch x(t+2) -> xTl (xTl free: all x-waves' reads done at
            // bar1); per-wave vmcnt(0) before bar2 => all writes landed
            // before any x-wave reads xTl in next P.
            if (t < SEQL - 2) {
#pragma unroll
                for (int i = 0; i < 8; ++i) {
                    int r = wq * 8 + i, b16 = r >> 1, half = r & 1;
                    const unsigned short* src =
                        Xb + ((size_t)(jb * 16 + b16) * 512 + (t + 2)) * 1024 + half * 512 + l * 8;
                    gld_lds16(src, &xTl[b16 * 1032 + half * 512]);
                }
            }
            asm volatile("s_waitcnt vmcnt(0)" ::: "memory");
        }
        __syncthreads();   // bar2

        // ===================== region S =====================
        // store h(t+1) chunk (64 thr x 8B = 4 full 128B lines) + poison
        // retired buf[(t-1)&3]. vmcnt(0) drains prior poison first.
        if (tid < 64) {
            int b = tid >> 2, l4 = tid & 3;
            unsigned long long v = *(const unsigned long long*)(&hTr[b * 20 + l4 * 4]);
            asm volatile("s_waitcnt vmcnt(0)" ::: "memory");
            size_t u = (size_t)(jb * 64 + ibb) * 64 + b * 4 + l4;
            __hip_atomic_store(hb64 + (size_t)((t + 1) & 3) * BUFU64 + u, v,
                               __ATOMIC_RELAXED, __HIP_MEMORY_SCOPE_AGENT);
            __hip_atomic_store(hb64 + (size_t)((t + 3) & 3) * BUFU64 + u, POISON,
                               __ATOMIC_RELAXED, __HIP_MEMORY_SCOPE_AGENT);
        }
    }
    // t=511 stores h(512) into buf[512&3] = buf0: final h at hbuf base
}

// --- output: out[b][o] = sum_k h[b][k] * w[o][k]  (chunk-layout source)
__global__ __launch_bounds__(256) void k_out(const unsigned short* __restrict__ hT,
                                             const float* __restrict__ wT,
                                             float* __restrict__ out) {
    const int b = blockIdx.x;
    const int jb = b >> 4, b16 = b & 15;
    const int tid = threadIdx.x;
    __shared__ float hs[1024];
#pragma unroll
    for (int p = 0; p < 4; ++p) {
        int k = p * 256 + tid;
        hs[k] = bf2f(hT[(size_t)(jb * 64 + (k >> 4)) * 256 + b16 * 16 + (k & 15)]);
    }
    __syncthreads();
    float a0 = 0.f, a1 = 0.f;
    for (int k = 0; k < 1024; ++k) {
        float hv = hs[k];
        a0 = fmaf(hv, wT[k * 512 + tid], a0);
        a1 = fmaf(hv, wT[k * 512 + 256 + tid], a1);
    }
    out[b * 512 + tid] = a0;
    out[b * 512 + 256 + tid] = a1;
}

extern "C" void kernel_launch(void* const* d_in, const int* in_sizes, int n_in,
                              void* d_out, int out_size, void* d_ws, size_t ws_size,
                              hipStream_t stream) {
    const float* X    = (const float*)d_in[0];
    const float* c0   = (const float*)d_in[1];
    const float* h0   = (const float*)d_in[2];
    const float* w_hi = (const float*)d_in[3];
    const float* w_xi = (const float*)d_in[4];
    const float* b_hi = (const float*)d_in[5];
    const float* b_xi = (const float*)d_in[6];
    const float* w_hf = (const float*)d_in[7];
    const float* w_xf = (const float*)d_in[8];
    const float* b_hf = (const float*)d_in[9];
    const float* b_xf = (const float*)d_in[10];
    const float* w_ho = (const float*)d_in[11];
    const float* w_xo = (const float*)d_in[12];
    const float* b_ho = (const float*)d_in[13];
    const float* b_xo = (const float*)d_in[14];
    const float* w_hg = (const float*)d_in[15];
    const float* w_xg = (const float*)d_in[16];
    const float* b_hg = (const float*)d_in[17];
    const float* b_xg = (const float*)d_in[18];
    const float* w    = (const float*)d_in[19];

    // workspace layout (16B aligned); ~83 MiB
    char* ws = (char*)d_ws;
    size_t off = 0;
    unsigned short* Whp = (unsigned short*)(ws + off); off += (size_t)4096 * 1024 * 2;
    unsigned short* Wxp = (unsigned short*)(ws + off); off += (size_t)4096 * 1024 * 2;
    unsigned short* Xb  = (unsigned short*)(ws + off); off += (size_t)64 * 512 * 1024 * 2;
    float*          bias= (float*)(ws + off);          off += (size_t)4096 * 4;
    float*          wT  = (float*)(ws + off);          off += (size_t)1024 * 512 * 4;
    unsigned short* hbuf= (unsigned short*)(ws + off); off += (size_t)4 * 64 * 1024 * 2;
    if (ws_size < off) return;

    k_pack_w<<<4096, 256, 0, stream>>>(w_hi, w_hf, w_ho, w_hg, Whp);
    k_pack_w<<<4096, 256, 0, stream>>>(w_xi, w_xf, w_xo, w_xg, Wxp);
    k_misc<<<(4096 + 65536 + 524288 + 3 * BUFU64 + 255) / 256, 256, 0, stream>>>(
        b_hi, b_xi, b_hf, b_xf, b_ho, b_xo, b_hg, b_xg, h0, w, bias, hbuf, wT);
    k_convert_x<<<33554432 / 4 / 256, 256, 0, stream>>>(X, Xb);

    // Plain launch: 256 blocks, 1/CU, all co-resident structurally.
    k_rec<<<dim3(256), dim3(512), 0, stream>>>(Whp, Wxp, Xb, bias, c0, hbuf);

    k_out<<<64, 256, 0, stream>>>(hbuf, wT, (float*)d_out);
}